// Round 6
// baseline (1033.858 us; speedup 1.0000x reference)
//
#include <hip/hip_runtime.h>
#include <math.h>

#define NROWS 32768
#define DIM   256
#define KCODES 1024
#define RPB   32      // rows per block
#define CANDC 12      // candidate cap per row

// ---- ws layout (bytes) ----
//      0 : double loss accumulator
//     16 : se[1024]   f32  (np-exact codebook row sum-of-squares)
// 270352 : cb_bf16[1024*256] ushort (RTNE bf16 codebook, B-FRAGMENT order)
#define WS_SE    16
#define WS_CBBF  270352

typedef __attribute__((ext_vector_type(8))) short  short8;
typedef __attribute__((ext_vector_type(4))) float  f32x4;

__device__ __forceinline__ unsigned short bf16rtne(float f){
    unsigned int u = __float_as_uint(f);
    return (unsigned short)((u + 0x7FFFu + ((u >> 16) & 1u)) >> 16);
}

__device__ __forceinline__ void gload_lds16(const void* g, void* l){
    __builtin_amdgcn_global_load_lds(
        (const __attribute__((address_space(1))) void*)g,
        (__attribute__((address_space(3))) void*)l, 16, 0, 0);
}

// Fused prep: zero loss acc; np-exact se (codebook row sum-of-squares);
// codebook -> bf16 in MFMA B-fragment order:
//   dst[((T*8+s)*64 + lane)*8 + e] = bf16(cb[(T*16+(lane&15))*256 + s*32 + (lane>>4)*8 + e])
__global__ void prep_kernel(const float* __restrict__ cb,
                            float* __restrict__ se,
                            unsigned short* __restrict__ cbbf,
                            double* __restrict__ acc) {
    const int tid  = threadIdx.x;
    const int gtid = blockIdx.x * 256 + tid;
    if (gtid == 0) *acc = 0.0;

    // --- np-exact pairwise row sum-of-squares for 1024 codebook rows ---
    {
        const int wave = gtid >> 6;          // 0..255
        const int lane = tid & 63;
        const int rowsub = lane >> 4;
        const int agent  = lane & 15;
        const int half   = agent >> 3;
        const int j      = agent & 7;
        const int row = wave * 4 + rowsub;   // < 1024
        const float* p = cb + (size_t)row * DIM + half * 128 + j;
        float x0 = p[0];
        float r  = __fmul_rn(x0, x0);
        #pragma unroll
        for (int i = 1; i < 16; ++i) {
            float xi = p[8 * i];
            r = __fadd_rn(r, __fmul_rn(xi, xi));
        }
        r = __fadd_rn(r, __shfl_xor(r, 1, 64));
        r = __fadd_rn(r, __shfl_xor(r, 2, 64));
        r = __fadd_rn(r, __shfl_xor(r, 4, 64));
        r = __fadd_rn(r, __shfl_xor(r, 8, 64));
        if (agent == 0) se[row] = r;
    }

    // --- bf16 fragment-order conversion (2 short8 units per thread) ---
    #pragma unroll
    for (int rep = 0; rep < 2; ++rep) {
        int o = gtid + rep * 16384;          // 0..32767
        int lane = o & 63;
        int ts   = o >> 6;                   // T*8 + s
        int code = (ts >> 3) * 16 + (lane & 15);
        int k0   = (ts & 7) * 32 + (lane >> 4) * 8;
        const float4* p = (const float4*)(cb + (size_t)code * DIM + k0);
        float4 a = p[0], b = p[1];
        short8 f;
        f[0] = (short)bf16rtne(a.x); f[1] = (short)bf16rtne(a.y);
        f[2] = (short)bf16rtne(a.z); f[3] = (short)bf16rtne(a.w);
        f[4] = (short)bf16rtne(b.x); f[5] = (short)bf16rtne(b.y);
        f[6] = (short)bf16rtne(b.z); f[7] = (short)bf16rtne(b.w);
        *(short8*)(cbbf + (size_t)o * 8) = f;
    }
}

#define FMA4(A, X, E) do {                                       \
    A.x = fmaf(X.x, E.x, A.x); A.y = fmaf(X.y, E.y, A.y);        \
    A.z = fmaf(X.z, E.z, A.z); A.w = fmaf(X.w, E.w, A.w);        \
} while (0)

// 1024 blocks x 4 waves, 32 rows/block. ONE MFMA pass: per (lane,row) stream
// track u = se - 2*dot (sx-free, range ~±0.05): running min u1 + its tile t1
// + second-min u2. Candidates = stream minima within the rigorous margin;
// u2-in-margin (rare) forces the row into the exact full-1024 rescan.
// B streamed via gload_lds, ring-3 4KB chunks, lookahead-2, counted vmcnt,
// no barriers in the main loop. Pass C = verified exact fp32 rescore.
__launch_bounds__(256, 2)
__global__ void vq_score(const float* __restrict__ x,
                         const float* __restrict__ cb,
                         const float* __restrict__ se_arr,
                         const unsigned short* __restrict__ cbbf,
                         float* __restrict__ out_q,
                         float* __restrict__ out_idx,
                         double* __restrict__ loss_acc)
{
    // wave-private ring buffers: [wave][ring 0..2][k-substep][lane] = short8
    __shared__ short8 bufs[4][3][4][64];     // 49152 B
    __shared__ float minw[4][RPB];
    __shared__ float thr[RPB];
    __shared__ float sxl[RPB];
    __shared__ float sal[RPB];
    __shared__ unsigned int cnt[RPB];
    __shared__ unsigned int cand[RPB][CANDC];
    __shared__ unsigned long long win[RPB];
    __shared__ unsigned int wcode[RPB];
    __shared__ double lsum[4];

    const int tid  = threadIdx.x;
    const int w    = tid >> 6;
    const int lane = tid & 63;
    const int cc   = lane & 15;
    const int g    = lane >> 4;
    const int n0   = blockIdx.x * RPB;

    if (tid < RPB) { cnt[tid] = 0u; win[tid] = ~0ull; }

    // ---- A fragments: rows rt*16+cc, k = 32s + 8g + e (verified mapping) ----
    short8 afrag[2][8];
    #pragma unroll
    for (int rt = 0; rt < 2; ++rt) {
        const float4* rp = (const float4*)x + (size_t)(n0 + rt * 16 + cc) * 64;
        #pragma unroll
        for (int s = 0; s < 8; ++s) {
            float4 a = rp[s * 8 + g * 2];
            float4 b = rp[s * 8 + g * 2 + 1];
            short8 f;
            f[0] = (short)bf16rtne(a.x); f[1] = (short)bf16rtne(a.y);
            f[2] = (short)bf16rtne(a.z); f[3] = (short)bf16rtne(a.w);
            f[4] = (short)bf16rtne(b.x); f[5] = (short)bf16rtne(b.y);
            f[6] = (short)bf16rtne(b.z); f[7] = (short)bf16rtne(b.w);
            afrag[rt][s] = f;
        }
    }

    // ---- fused np-exact row sums (identical instruction sequence) ----
    {
        const int rowsub = lane >> 4;
        const int agent  = lane & 15;
        const int half   = agent >> 3;
        const int j      = agent & 7;
        #pragma unroll
        for (int q = 0; q < 2; ++q) {
            const int lrow = w * 8 + q * 4 + rowsub;
            const float* p = x + (size_t)(n0 + lrow) * DIM + half * 128 + j;
            float x0 = p[0];
            float r  = __fmul_rn(x0, x0);
            float ra = fabsf(x0);
            #pragma unroll
            for (int i = 1; i < 16; ++i) {
                float xi = p[8 * i];
                r  = __fadd_rn(r, __fmul_rn(xi, xi));
                ra += fabsf(xi);
            }
            r = __fadd_rn(r, __shfl_xor(r, 1, 64));  ra += __shfl_xor(ra, 1, 64);
            r = __fadd_rn(r, __shfl_xor(r, 2, 64));  ra += __shfl_xor(ra, 2, 64);
            r = __fadd_rn(r, __shfl_xor(r, 4, 64));  ra += __shfl_xor(ra, 4, 64);
            r = __fadd_rn(r, __shfl_xor(r, 8, 64));  ra += __shfl_xor(ra, 8, 64);
            if (agent == 0) { sxl[lrow] = r; sal[lrow] = ra; }
        }
    }

    const int T0 = w << 4;        // wave's first 16-code tile index
    const f32x4 fz = {0.f, 0.f, 0.f, 0.f};

    // se for the wave's 256-code slice: statically-indexed registers
    float se_reg[16];
    #pragma unroll
    for (int t = 0; t < 16; ++t) se_reg[t] = se_arr[(T0 + t) * 16 + cc];

    // per (lane,row) stream tracker: min u, its tile, second-min u
    float u1g[2][4], u2g[2][4], t1g[2][4];
    #pragma unroll
    for (int rt = 0; rt < 2; ++rt)
        #pragma unroll
        for (int r = 0; r < 4; ++r) {
            u1g[rt][r] = INFINITY; u2g[rt][r] = INFINITY; t1g[rt][r] = 0.f;
        }
    f32x4 a0 = fz, a1 = fz;

// chunk c (0..31): tile t = c>>1, half h = c&1 (k-steps h*4..h*4+3), ring c%3
#define ISSUE_C(c) do {                                                       \
    const char* gsrc_ = (const char*)cbbf +                                   \
        (size_t)(((T0 + ((c) >> 1)) * 8 + ((c) & 1) * 4)) * 1024 + lane * 16; \
    _Pragma("unroll")                                                         \
    for (int i_ = 0; i_ < 4; ++i_)                                            \
        gload_lds16(gsrc_ + i_ * 1024, (void*)&bufs[w][(c) % 3][i_][0]);      \
} while (0)

#define WAITV_(N) asm volatile("s_waitcnt vmcnt(" #N ")" ::: "memory")
#define WAITV(N) WAITV_(N)
#define LGKM0 asm volatile("s_waitcnt lgkmcnt(0)" ::: "memory")

#define MFMA4(c) do {                                                         \
    short8 bv_[4];                                                            \
    _Pragma("unroll")                                                         \
    for (int s_ = 0; s_ < 4; ++s_) bv_[s_] = bufs[w][(c) % 3][s_][lane];      \
    _Pragma("unroll")                                                         \
    for (int s_ = 0; s_ < 4; ++s_) {                                          \
        const int ks_ = ((c) & 1) * 4 + s_;                                   \
        a0 = __builtin_amdgcn_mfma_f32_16x16x32_bf16(afrag[0][ks_], bv_[s_], a0, 0, 0, 0); \
        a1 = __builtin_amdgcn_mfma_f32_16x16x32_bf16(afrag[1][ks_], bv_[s_], a1, 0, 0, 0); \
    }                                                                         \
} while (0)

// u = se - 2*dot; branchless top-2 tracker (invariant u1 <= u2)
#define EPI(t) do {                                                           \
    const float sec_ = se_reg[(t)];                                           \
    const float tf_  = (float)(t);                                            \
    _Pragma("unroll")                                                         \
    for (int r_ = 0; r_ < 4; ++r_) {                                          \
        float ua_ = fmaf(-2.f, a0[r_], sec_);                                 \
        float ub_ = fmaf(-2.f, a1[r_], sec_);                                 \
        bool la_ = ua_ < u1g[0][r_];                                          \
        u2g[0][r_] = fminf(u2g[0][r_], fmaxf(u1g[0][r_], ua_));               \
        t1g[0][r_] = la_ ? tf_ : t1g[0][r_];                                  \
        u1g[0][r_] = fminf(u1g[0][r_], ua_);                                  \
        bool lb_ = ub_ < u1g[1][r_];                                          \
        u2g[1][r_] = fminf(u2g[1][r_], fmaxf(u1g[1][r_], ub_));               \
        t1g[1][r_] = lb_ ? tf_ : t1g[1][r_];                                  \
        u1g[1][r_] = fminf(u1g[1][r_], ub_);                                  \
    }                                                                         \
} while (0)

// lgkmcnt(0): ds_reads of the chunk whose ring slot we overwrite are done.
#define STEP(c, W) do {                                                       \
    LGKM0;                                                                    \
    if ((c) + 2 < 32) ISSUE_C((c) + 2);                                       \
    WAITV(W);                                                                 \
    if (((c) & 1) == 0) { a0 = fz; a1 = fz; }                                 \
    MFMA4(c);                                                                 \
    if (((c) & 1) == 1) EPI((c) >> 1);                                        \
} while (0)

    // ---- single MFMA pass: lookahead-2 counted-vmcnt pipeline, no barriers ----
    WAITV(0);              // drain pre-loop VMEM so counts are exact
    ISSUE_C(0); ISSUE_C(1);
    STEP(0, 8);  STEP(1, 8);  STEP(2, 8);  STEP(3, 8);
    STEP(4, 8);  STEP(5, 8);  STEP(6, 8);  STEP(7, 8);
    STEP(8, 8);  STEP(9, 8);  STEP(10, 8); STEP(11, 8);
    STEP(12, 8); STEP(13, 8); STEP(14, 8); STEP(15, 8);
    STEP(16, 8); STEP(17, 8); STEP(18, 8); STEP(19, 8);
    STEP(20, 8); STEP(21, 8); STEP(22, 8); STEP(23, 8);
    STEP(24, 8); STEP(25, 8); STEP(26, 8); STEP(27, 8);
    STEP(28, 8); STEP(29, 8); STEP(30, 4); STEP(31, 0);

    // ---- per-row u-min across the 16 cc-lanes, then across waves ----
    #pragma unroll
    for (int rt = 0; rt < 2; ++rt) {
        #pragma unroll
        for (int r = 0; r < 4; ++r) {
            float v = u1g[rt][r];
            v = fminf(v, __shfl_xor(v, 1, 64));
            v = fminf(v, __shfl_xor(v, 2, 64));
            v = fminf(v, __shfl_xor(v, 4, 64));
            v = fminf(v, __shfl_xor(v, 8, 64));
            if (cc == 0) minw[w][rt * 16 + g * 4 + r] = v;
        }
    }
    __syncthreads();
    if (tid < RPB) {
        float umin = fminf(fminf(minw[0][tid], minw[1][tid]),
                           fminf(minw[2][tid], minw[3][tid]));
        // margin: 2*(bf16 dot err, <= sa*7.7e-6) + f32 big-op rounding slack
        thr[tid] = umin + fmaf(sal[tid], 1.6e-5f, 1.0e-4f);
    }
    __syncthreads();

    // ---- candidate emission from stream trackers (pass B eliminated) ----
    #pragma unroll
    for (int rt = 0; rt < 2; ++rt) {
        #pragma unroll
        for (int r = 0; r < 4; ++r) {
            const int row = rt * 16 + g * 4 + r;
            const float tu = thr[row];
            if (u1g[rt][r] <= tu) {
                unsigned int code =
                    (unsigned int)((T0 + (int)t1g[rt][r]) * 16 + cc);
                unsigned int p = atomicAdd(&cnt[row], 1u);
                if (p < (unsigned)CANDC) cand[row][p] = code;
            }
            if (u2g[rt][r] <= tu)      // 2 in-margin codes in one stream:
                atomicAdd(&cnt[row], 256u);   // force exact full rescan
        }
    }
    __syncthreads();

    // ---- PASS C: exact fp32 rescore of candidates (tie -> lower code) ----
    {
        const int r  = tid >> 3;
        const int sl = tid & 7;
        const unsigned int n = cnt[r];
        const bool ovf = (n > (unsigned)CANDC);
        const unsigned int total = ovf ? (unsigned)KCODES : n;
        const float sxr = sxl[r];
        const float4* xr  = (const float4*)x + (size_t)(n0 + r) * 64;
        const float4* cb4 = (const float4*)cb;
        for (unsigned int j = sl; j < total; j += 8) {
            unsigned int code = ovf ? j : cand[r][j];
            const float4* er = cb4 + (size_t)code * 64;
            float4 a4 = make_float4(0.f, 0.f, 0.f, 0.f);
            #pragma unroll 8
            for (int m2 = 0; m2 < 64; ++m2) {
                float4 xv = xr[m2];
                float4 ev = er[m2];
                FMA4(a4, xv, ev);
            }
            float dot  = (a4.x + a4.y) + (a4.z + a4.w);
            float tt   = __fadd_rn(sxr, se_arr[code]);
            float dist = __fsub_rn(tt, 2.0f * dot);
            unsigned long long pk =
                ((unsigned long long)__float_as_uint(dist) << 32) | (unsigned long long)code;
            atomicMin(&win[r], pk);
        }
    }
    __syncthreads();
    if (tid < RPB) {
        unsigned int code = (unsigned int)(win[tid] & 0xFFFFFFFFull);
        wcode[tid] = code;
        out_idx[n0 + tid] = (float)code;
    }
    __syncthreads();

    // ---- outputs (bit-exact straight-through) + fp64 loss partial ----
    double lacc = 0.0;
    {
        const float4* x4  = (const float4*)x;
        const float4* cb4 = (const float4*)cb;
        float4* q4 = (float4*)out_q;
        #pragma unroll
        for (int i = 0; i < 8; ++i) {
            int flat = tid + 256 * i;       // 0..2047 (32 rows x 64 float4)
            int row  = flat >> 6;
            int d4   = flat & 63;
            float4 xv = x4[(size_t)n0 * 64 + flat];
            float4 qv = cb4[(size_t)wcode[row] * 64 + d4];
            float dfx = __fsub_rn(qv.x, xv.x);
            float dfy = __fsub_rn(qv.y, xv.y);
            float dfz = __fsub_rn(qv.z, xv.z);
            float dfw = __fsub_rn(qv.w, xv.w);
            float4 o;
            o.x = __fadd_rn(xv.x, dfx);
            o.y = __fadd_rn(xv.y, dfy);
            o.z = __fadd_rn(xv.z, dfz);
            o.w = __fadd_rn(xv.w, dfw);
            lacc += (double)dfx * dfx + (double)dfy * dfy
                  + (double)dfz * dfz + (double)dfw * dfw;
            q4[(size_t)n0 * 64 + flat] = o;
        }
    }
    #pragma unroll
    for (int off = 32; off > 0; off >>= 1)
        lacc += __shfl_down(lacc, off, 64);
    if (lane == 0) lsum[w] = lacc;
    __syncthreads();
    if (tid == 0)
        atomicAdd(loss_acc, (lsum[0] + lsum[1]) + (lsum[2] + lsum[3]));
}

__global__ void finalize_loss(const double* __restrict__ acc,
                              float* __restrict__ out_loss) {
    if (threadIdx.x == 0 && blockIdx.x == 0)
        *out_loss = (float)(*acc / (double)(NROWS * DIM));
}

extern "C" void kernel_launch(void* const* d_in, const int* in_sizes, int n_in,
                              void* d_out, int out_size, void* d_ws, size_t ws_size,
                              hipStream_t stream) {
    const float* x  = (const float*)d_in[0];
    const float* cb = (const float*)d_in[1];
    float* out      = (float*)d_out;
    float* out_q    = out;                        // 8388608 elements
    float* out_idx  = out + (size_t)NROWS * DIM;  // 32768 elements (as float)
    float* out_loss = out_idx + NROWS;            // 1 element

    char* ws = (char*)d_ws;
    double* acc = (double*)ws;
    float* se   = (float*)(ws + WS_SE);
    unsigned short* cbbf = (unsigned short*)(ws + WS_CBBF);

    prep_kernel<<<64, 256, 0, stream>>>(cb, se, cbbf, acc);
    vq_score<<<NROWS / RPB, 256, 0, stream>>>(x, cb, se, cbbf,
                                              out_q, out_idx, acc);
    finalize_loss<<<1, 1, 0, stream>>>(acc, out_loss);
}

// Round 8
// 980.558 us; speedup vs baseline: 1.0544x; 1.0544x over previous
//
#include <hip/hip_runtime.h>
#include <math.h>

#define NROWS 32768
#define DIM   256
#define KCODES 1024
#define RPB   32      // rows per block
#define CANDC 12      // candidate cap per row

// ---- ws layout (bytes) ----
//      0 : double loss accumulator
//     16 : se[1024]   f32  (np-exact codebook row sum-of-squares)
// 270352 : cb_bf16[1024*256] ushort (RTNE bf16 codebook, B-FRAGMENT order)
#define WS_SE    16
#define WS_CBBF  270352

typedef __attribute__((ext_vector_type(8))) short  short8;
typedef __attribute__((ext_vector_type(4))) float  f32x4;

__device__ __forceinline__ unsigned short bf16rtne(float f){
    unsigned int u = __float_as_uint(f);
    return (unsigned short)((u + 0x7FFFu + ((u >> 16) & 1u)) >> 16);
}

__device__ __forceinline__ void gload_lds16(const void* g, void* l){
    __builtin_amdgcn_global_load_lds(
        (const __attribute__((address_space(1))) void*)g,
        (__attribute__((address_space(3))) void*)l, 16, 0, 0);
}

// monotone float->uint order key (u < v  <=>  fkey(u) < fkey(v))
__device__ __forceinline__ unsigned fkey(float f){
    unsigned ub = __float_as_uint(f);
    return ub ^ (0x80000000u | (unsigned)((int)ub >> 31));
}
// decode a key with its low 4 bits (tile id) cleared; dec(k) in [u-eps, u]
__device__ __forceinline__ float fdec(unsigned k){
    unsigned v = k & 0xFFFFFFF0u;
    unsigned ub = (v & 0x80000000u) ? (v ^ 0x80000000u) : ~v;
    return __uint_as_float(ub);
}

// Fused prep: zero loss acc; np-exact se (codebook row sum-of-squares);
// codebook -> bf16 in MFMA B-fragment order:
//   dst[((T*8+s)*64 + lane)*8 + e] = bf16(cb[(T*16+(lane&15))*256 + s*32 + (lane>>4)*8 + e])
__global__ void prep_kernel(const float* __restrict__ cb,
                            float* __restrict__ se,
                            unsigned short* __restrict__ cbbf,
                            double* __restrict__ acc) {
    const int tid  = threadIdx.x;
    const int gtid = blockIdx.x * 256 + tid;
    if (gtid == 0) *acc = 0.0;

    // --- np-exact pairwise row sum-of-squares for 1024 codebook rows ---
    {
        const int wave = gtid >> 6;          // 0..255
        const int lane = tid & 63;
        const int rowsub = lane >> 4;
        const int agent  = lane & 15;
        const int half   = agent >> 3;
        const int j      = agent & 7;
        const int row = wave * 4 + rowsub;   // < 1024
        const float* p = cb + (size_t)row * DIM + half * 128 + j;
        float x0 = p[0];
        float r  = __fmul_rn(x0, x0);
        #pragma unroll
        for (int i = 1; i < 16; ++i) {
            float xi = p[8 * i];
            r = __fadd_rn(r, __fmul_rn(xi, xi));
        }
        r = __fadd_rn(r, __shfl_xor(r, 1, 64));
        r = __fadd_rn(r, __shfl_xor(r, 2, 64));
        r = __fadd_rn(r, __shfl_xor(r, 4, 64));
        r = __fadd_rn(r, __shfl_xor(r, 8, 64));
        if (agent == 0) se[row] = r;
    }

    // --- bf16 fragment-order conversion (2 short8 units per thread) ---
    #pragma unroll
    for (int rep = 0; rep < 2; ++rep) {
        int o = gtid + rep * 16384;          // 0..32767
        int lane = o & 63;
        int ts   = o >> 6;                   // T*8 + s
        int code = (ts >> 3) * 16 + (lane & 15);
        int k0   = (ts & 7) * 32 + (lane >> 4) * 8;
        const float4* p = (const float4*)(cb + (size_t)code * DIM + k0);
        float4 a = p[0], b = p[1];
        short8 f;
        f[0] = (short)bf16rtne(a.x); f[1] = (short)bf16rtne(a.y);
        f[2] = (short)bf16rtne(a.z); f[3] = (short)bf16rtne(a.w);
        f[4] = (short)bf16rtne(b.x); f[5] = (short)bf16rtne(b.y);
        f[6] = (short)bf16rtne(b.z); f[7] = (short)bf16rtne(b.w);
        *(short8*)(cbbf + (size_t)o * 8) = f;
    }
}

#define FMA4(A, X, E) do {                                       \
    A.x = fmaf(X.x, E.x, A.x); A.y = fmaf(X.y, E.y, A.y);        \
    A.z = fmaf(X.z, E.z, A.z); A.w = fmaf(X.w, E.w, A.w);        \
} while (0)

// 1024 blocks x 4 waves, 32 rows/block — R4's verified staging (dbuf 8KB
// tiles, lookahead-1, counted vmcnt(8), no barriers, VGPR-lean) with a
// register-NEUTRAL single-pass argmin: per (lane,row) stream track packed
// keys k1 (min u=se-2*dot, tile in low 4 bits) and k2 (second-min). 16
// uints exactly replace R4's 16-float tilemin. Pass B deleted; candidates
// come from k1; a k2-in-margin stream forces the exact full-1024 rescan.
__launch_bounds__(256, 2)
__global__ void vq_score(const float* __restrict__ x,
                         const float* __restrict__ cb,
                         const float* __restrict__ se_arr,
                         const unsigned short* __restrict__ cbbf,
                         float* __restrict__ out_q,
                         float* __restrict__ out_idx,
                         double* __restrict__ loss_acc)
{
    // wave-private double buffers: [wave][buf][k-step s][lane] = short8
    __shared__ short8 bufs[4][2][8][64];     // 65536 B
    __shared__ float minw[4][RPB];
    __shared__ float thr[RPB];
    __shared__ float sxl[RPB];
    __shared__ float sal[RPB];
    __shared__ unsigned int cnt[RPB];
    __shared__ unsigned int cand[RPB][CANDC];
    __shared__ unsigned long long win[RPB];
    __shared__ unsigned int wcode[RPB];
    __shared__ double lsum[4];

    const int tid  = threadIdx.x;
    const int w    = tid >> 6;
    const int lane = tid & 63;
    const int cc   = lane & 15;
    const int g    = lane >> 4;
    const int n0   = blockIdx.x * RPB;

    if (tid < RPB) { cnt[tid] = 0u; win[tid] = ~0ull; }

    // ---- A fragments: rows rt*16+cc, k = 32s + 8g + e (verified mapping) ----
    short8 afrag[2][8];
    #pragma unroll
    for (int rt = 0; rt < 2; ++rt) {
        const float4* rp = (const float4*)x + (size_t)(n0 + rt * 16 + cc) * 64;
        #pragma unroll
        for (int s = 0; s < 8; ++s) {
            float4 a = rp[s * 8 + g * 2];
            float4 b = rp[s * 8 + g * 2 + 1];
            short8 f;
            f[0] = (short)bf16rtne(a.x); f[1] = (short)bf16rtne(a.y);
            f[2] = (short)bf16rtne(a.z); f[3] = (short)bf16rtne(a.w);
            f[4] = (short)bf16rtne(b.x); f[5] = (short)bf16rtne(b.y);
            f[6] = (short)bf16rtne(b.z); f[7] = (short)bf16rtne(b.w);
            afrag[rt][s] = f;
        }
    }

    // ---- fused np-exact row sums (identical instruction sequence) ----
    {
        const int rowsub = lane >> 4;
        const int agent  = lane & 15;
        const int half   = agent >> 3;
        const int j      = agent & 7;
        #pragma unroll
        for (int q = 0; q < 2; ++q) {
            const int lrow = w * 8 + q * 4 + rowsub;
            const float* p = x + (size_t)(n0 + lrow) * DIM + half * 128 + j;
            float x0 = p[0];
            float r  = __fmul_rn(x0, x0);
            float ra = fabsf(x0);
            #pragma unroll
            for (int i = 1; i < 16; ++i) {
                float xi = p[8 * i];
                r  = __fadd_rn(r, __fmul_rn(xi, xi));
                ra += fabsf(xi);
            }
            r = __fadd_rn(r, __shfl_xor(r, 1, 64));  ra += __shfl_xor(ra, 1, 64);
            r = __fadd_rn(r, __shfl_xor(r, 2, 64));  ra += __shfl_xor(ra, 2, 64);
            r = __fadd_rn(r, __shfl_xor(r, 4, 64));  ra += __shfl_xor(ra, 4, 64);
            r = __fadd_rn(r, __shfl_xor(r, 8, 64));  ra += __shfl_xor(ra, 8, 64);
            if (agent == 0) { sxl[lrow] = r; sal[lrow] = ra; }
        }
    }

    const int T0 = w << 4;        // wave's first 16-code tile index
    const f32x4 fz = {0.f, 0.f, 0.f, 0.f};

    // se for the wave's 256-code slice: statically-indexed registers
    float se_reg[16];
    #pragma unroll
    for (int t = 0; t < 16; ++t) se_reg[t] = se_arr[(T0 + t) * 16 + cc];

    // packed top-2 trackers per (lane,row) stream (16 uints total)
    unsigned k1[2][4], k2[2][4];
    #pragma unroll
    for (int rt = 0; rt < 2; ++rt)
        #pragma unroll
        for (int r = 0; r < 4; ++r) { k1[rt][r] = ~0u; k2[rt][r] = ~0u; }

#define ISSUE(T) do {                                                         \
    const char* gsrc_ = (const char*)cbbf + (size_t)(T0 + (T)) * 8192 + lane * 16; \
    _Pragma("unroll")                                                         \
    for (int i_ = 0; i_ < 8; ++i_)                                            \
        gload_lds16(gsrc_ + i_ * 1024, (void*)&bufs[w][(T) & 1][i_][0]);      \
} while (0)

#define WAITV_(N) asm volatile("s_waitcnt vmcnt(" #N ")" ::: "memory")
#define WAITV(N) WAITV_(N)
#define LGKM0 asm volatile("s_waitcnt lgkmcnt(0)" ::: "memory")

#define COMPUTE(T) do {                                                       \
    short8 bv_[8];                                                            \
    _Pragma("unroll")                                                         \
    for (int s_ = 0; s_ < 8; ++s_) bv_[s_] = bufs[w][(T) & 1][s_][lane];      \
    f32x4 a0_ = fz, a1_ = fz;                                                 \
    _Pragma("unroll")                                                         \
    for (int s_ = 0; s_ < 8; ++s_) {                                          \
        a0_ = __builtin_amdgcn_mfma_f32_16x16x32_bf16(afrag[0][s_], bv_[s_], a0_, 0, 0, 0); \
        a1_ = __builtin_amdgcn_mfma_f32_16x16x32_bf16(afrag[1][s_], bv_[s_], a1_, 0, 0, 0); \
    }                                                                         \
    const float sec_ = se_reg[(T)];                                           \
    _Pragma("unroll")                                                         \
    for (int r_ = 0; r_ < 4; ++r_) {                                          \
        float ua_ = fmaf(-2.f, a0_[r_], sec_);                                \
        float ub_ = fmaf(-2.f, a1_[r_], sec_);                                \
        unsigned ka_ = (fkey(ua_) & 0xFFFFFFF0u) | (unsigned)(T);             \
        unsigned kb_ = (fkey(ub_) & 0xFFFFFFF0u) | (unsigned)(T);             \
        unsigned mxa_ = (ka_ > k1[0][r_]) ? ka_ : k1[0][r_];                  \
        k1[0][r_] = (ka_ < k1[0][r_]) ? ka_ : k1[0][r_];                      \
        k2[0][r_] = (mxa_ < k2[0][r_]) ? mxa_ : k2[0][r_];                    \
        unsigned mxb_ = (kb_ > k1[1][r_]) ? kb_ : k1[1][r_];                  \
        k1[1][r_] = (kb_ < k1[1][r_]) ? kb_ : k1[1][r_];                      \
        k2[1][r_] = (mxb_ < k2[1][r_]) ? mxb_ : k2[1][r_];                    \
    }                                                                         \
} while (0)

// lgkmcnt(0): prev COMPUTE's ds_reads must land before overwriting its buf.
#define STEPW(T, W) do {                                                      \
    LGKM0;                                                                    \
    if ((T) < 15) ISSUE((T) + 1);                                             \
    WAITV(W);                                                                 \
    COMPUTE(T);                                                               \
} while (0)

    // ---- single MFMA pass: counted-vmcnt pipeline, no barriers ----
    WAITV(0);              // drain pre-loop VMEM so counts are exact
    ISSUE(0);
    STEPW(0, 8);  STEPW(1, 8);  STEPW(2, 8);  STEPW(3, 8);
    STEPW(4, 8);  STEPW(5, 8);  STEPW(6, 8);  STEPW(7, 8);
    STEPW(8, 8);  STEPW(9, 8);  STEPW(10, 8); STEPW(11, 8);
    STEPW(12, 8); STEPW(13, 8); STEPW(14, 8); STEPW(15, 0);

    // ---- per-row u-min across the 16 cc-lanes, then across waves ----
    #pragma unroll
    for (int rt = 0; rt < 2; ++rt) {
        #pragma unroll
        for (int r = 0; r < 4; ++r) {
            unsigned v = k1[rt][r];
            unsigned o;
            o = __shfl_xor(v, 1, 64); v = (o < v) ? o : v;
            o = __shfl_xor(v, 2, 64); v = (o < v) ? o : v;
            o = __shfl_xor(v, 4, 64); v = (o < v) ? o : v;
            o = __shfl_xor(v, 8, 64); v = (o < v) ? o : v;
            if (cc == 0) minw[w][rt * 16 + g * 4 + r] = fdec(v);
        }
    }
    __syncthreads();
    if (tid < RPB) {
        float umin = fminf(fminf(minw[0][tid], minw[1][tid]),
                           fminf(minw[2][tid], minw[3][tid]));
        // margin: 2*(bf16 dot err, <= sa*7.7e-6) + f32/key-quant rounding slack
        thr[tid] = umin + fmaf(sal[tid], 1.6e-5f, 1.0e-4f);
    }
    __syncthreads();

    // ---- candidate emission from stream trackers (no pass B) ----
    #pragma unroll
    for (int rt = 0; rt < 2; ++rt) {
        #pragma unroll
        for (int r = 0; r < 4; ++r) {
            const int row = rt * 16 + g * 4 + r;
            const float tu = thr[row];
            if (fdec(k1[rt][r]) <= tu) {
                unsigned code =
                    (unsigned)((T0 + (int)(k1[rt][r] & 15u)) * 16 + cc);
                unsigned p = atomicAdd(&cnt[row], 1u);
                if (p < (unsigned)CANDC) cand[row][p] = code;
            }
            if (fdec(k2[rt][r]) <= tu)    // 2 in-margin codes in one stream:
                atomicAdd(&cnt[row], 256u);   // force exact full rescan
        }
    }
    __syncthreads();

    // ---- PASS C: exact fp32 rescore of candidates (tie -> lower code) ----
    {
        const int r  = tid >> 3;
        const int sl = tid & 7;
        const unsigned int n = cnt[r];
        const bool ovf = (n > (unsigned)CANDC);
        const unsigned int total = ovf ? (unsigned)KCODES : n;
        const float sxr = sxl[r];
        const float4* xr  = (const float4*)x + (size_t)(n0 + r) * 64;
        const float4* cb4 = (const float4*)cb;
        for (unsigned int j = sl; j < total; j += 8) {
            unsigned int code = ovf ? j : cand[r][j];
            const float4* er = cb4 + (size_t)code * 64;
            float4 a4 = make_float4(0.f, 0.f, 0.f, 0.f);
            #pragma unroll 8
            for (int m2 = 0; m2 < 64; ++m2) {
                float4 xv = xr[m2];
                float4 ev = er[m2];
                FMA4(a4, xv, ev);
            }
            float dot  = (a4.x + a4.y) + (a4.z + a4.w);
            float tt   = __fadd_rn(sxr, se_arr[code]);
            float dist = __fsub_rn(tt, 2.0f * dot);
            unsigned long long pk =
                ((unsigned long long)__float_as_uint(dist) << 32) | (unsigned long long)code;
            atomicMin(&win[r], pk);
        }
    }
    __syncthreads();
    if (tid < RPB) {
        unsigned int code = (unsigned int)(win[tid] & 0xFFFFFFFFull);
        wcode[tid] = code;
        out_idx[n0 + tid] = (float)code;
    }
    __syncthreads();

    // ---- outputs (bit-exact straight-through) + fp64 loss partial ----
    double lacc = 0.0;
    {
        const float4* x4  = (const float4*)x;
        const float4* cb4 = (const float4*)cb;
        float4* q4 = (float4*)out_q;
        #pragma unroll
        for (int i = 0; i < 8; ++i) {
            int flat = tid + 256 * i;       // 0..2047 (32 rows x 64 float4)
            int row  = flat >> 6;
            int d4   = flat & 63;
            float4 xv = x4[(size_t)n0 * 64 + flat];
            float4 qv = cb4[(size_t)wcode[row] * 64 + d4];
            float dfx = __fsub_rn(qv.x, xv.x);
            float dfy = __fsub_rn(qv.y, xv.y);
            float dfz = __fsub_rn(qv.z, xv.z);
            float dfw = __fsub_rn(qv.w, xv.w);
            float4 o;
            o.x = __fadd_rn(xv.x, dfx);
            o.y = __fadd_rn(xv.y, dfy);
            o.z = __fadd_rn(xv.z, dfz);
            o.w = __fadd_rn(xv.w, dfw);
            lacc += (double)dfx * dfx + (double)dfy * dfy
                  + (double)dfz * dfz + (double)dfw * dfw;
            q4[(size_t)n0 * 64 + flat] = o;
        }
    }
    #pragma unroll
    for (int off = 32; off > 0; off >>= 1)
        lacc += __shfl_down(lacc, off, 64);
    if (lane == 0) lsum[w] = lacc;
    __syncthreads();
    if (tid == 0)
        atomicAdd(loss_acc, (lsum[0] + lsum[1]) + (lsum[2] + lsum[3]));
}

__global__ void finalize_loss(const double* __restrict__ acc,
                              float* __restrict__ out_loss) {
    if (threadIdx.x == 0 && blockIdx.x == 0)
        *out_loss = (float)(*acc / (double)(NROWS * DIM));
}

extern "C" void kernel_launch(void* const* d_in, const int* in_sizes, int n_in,
                              void* d_out, int out_size, void* d_ws, size_t ws_size,
                              hipStream_t stream) {
    const float* x  = (const float*)d_in[0];
    const float* cb = (const float*)d_in[1];
    float* out      = (float*)d_out;
    float* out_q    = out;                        // 8388608 elements
    float* out_idx  = out + (size_t)NROWS * DIM;  // 32768 elements (as float)
    float* out_loss = out_idx + NROWS;            // 1 element

    char* ws = (char*)d_ws;
    double* acc = (double*)ws;
    float* se   = (float*)(ws + WS_SE);
    unsigned short* cbbf = (unsigned short*)(ws + WS_CBBF);

    prep_kernel<<<64, 256, 0, stream>>>(cb, se, cbbf, acc);
    vq_score<<<NROWS / RPB, 256, 0, stream>>>(x, cb, se, cbbf,
                                              out_q, out_idx, acc);
    finalize_loss<<<1, 1, 0, stream>>>(acc, out_loss);
}

// Round 10
// 513.500 us; speedup vs baseline: 2.0134x; 1.9096x over previous
//
#include <hip/hip_runtime.h>
#include <math.h>

#define NROWS 32768
#define DIM   256
#define KCODES 1024
#define RPB   32      // rows per block
#define CANDC 24      // candidate cap per row (holds 1 flagged stream + extras)

// ---- ws layout (bytes) ----
//      0 : double loss accumulator
//     16 : se[1024]   f32  (np-exact codebook row sum-of-squares)
// 270352 : cb_bf16[1024*256] ushort (RTNE bf16 codebook, B-FRAGMENT order)
#define WS_SE    16
#define WS_CBBF  270352

typedef __attribute__((ext_vector_type(8))) short  short8;
typedef __attribute__((ext_vector_type(4))) float  f32x4;

__device__ __forceinline__ unsigned short bf16rtne(float f){
    unsigned int u = __float_as_uint(f);
    return (unsigned short)((u + 0x7FFFu + ((u >> 16) & 1u)) >> 16);
}

__device__ __forceinline__ void gload_lds16(const void* g, void* l){
    __builtin_amdgcn_global_load_lds(
        (const __attribute__((address_space(1))) void*)g,
        (__attribute__((address_space(3))) void*)l, 16, 0, 0);
}

// Fused prep: zero loss acc; np-exact se (codebook row sum-of-squares);
// codebook -> bf16 in MFMA B-fragment order:
//   dst[((T*8+s)*64 + lane)*8 + e] = bf16(cb[(T*16+(lane&15))*256 + s*32 + (lane>>4)*8 + e])
__global__ void prep_kernel(const float* __restrict__ cb,
                            float* __restrict__ se,
                            unsigned short* __restrict__ cbbf,
                            double* __restrict__ acc) {
    const int tid  = threadIdx.x;
    const int gtid = blockIdx.x * 256 + tid;
    if (gtid == 0) *acc = 0.0;

    // --- np-exact pairwise row sum-of-squares for 1024 codebook rows ---
    {
        const int wave = gtid >> 6;          // 0..255
        const int lane = tid & 63;
        const int rowsub = lane >> 4;
        const int agent  = lane & 15;
        const int half   = agent >> 3;
        const int j      = agent & 7;
        const int row = wave * 4 + rowsub;   // < 1024
        const float* p = cb + (size_t)row * DIM + half * 128 + j;
        float x0 = p[0];
        float r  = __fmul_rn(x0, x0);
        #pragma unroll
        for (int i = 1; i < 16; ++i) {
            float xi = p[8 * i];
            r = __fadd_rn(r, __fmul_rn(xi, xi));
        }
        r = __fadd_rn(r, __shfl_xor(r, 1, 64));
        r = __fadd_rn(r, __shfl_xor(r, 2, 64));
        r = __fadd_rn(r, __shfl_xor(r, 4, 64));
        r = __fadd_rn(r, __shfl_xor(r, 8, 64));
        if (agent == 0) se[row] = r;
    }

    // --- bf16 fragment-order conversion (2 short8 units per thread) ---
    #pragma unroll
    for (int rep = 0; rep < 2; ++rep) {
        int o = gtid + rep * 16384;          // 0..32767
        int lane = o & 63;
        int ts   = o >> 6;                   // T*8 + s
        int code = (ts >> 3) * 16 + (lane & 15);
        int k0   = (ts & 7) * 32 + (lane >> 4) * 8;
        const float4* p = (const float4*)(cb + (size_t)code * DIM + k0);
        float4 a = p[0], b = p[1];
        short8 f;
        f[0] = (short)bf16rtne(a.x); f[1] = (short)bf16rtne(a.y);
        f[2] = (short)bf16rtne(a.z); f[3] = (short)bf16rtne(a.w);
        f[4] = (short)bf16rtne(b.x); f[5] = (short)bf16rtne(b.y);
        f[6] = (short)bf16rtne(b.z); f[7] = (short)bf16rtne(b.w);
        *(short8*)(cbbf + (size_t)o * 8) = f;
    }
}

#define FMA4(A, X, E) do {                                       \
    A.x = fmaf(X.x, E.x, A.x); A.y = fmaf(X.y, E.y, A.y);        \
    A.z = fmaf(X.z, E.z, A.z); A.w = fmaf(X.w, E.w, A.w);        \
} while (0)

// 1024 blocks x 4 waves, 32 rows/block — R4's verified staging (dbuf 8KB
// tiles, lookahead-1, counted vmcnt(8), no barriers). Single-pass argmin
// tracker uses fminf-ONLY codegen (the R6/R8 cmp+cndmask spill trigger is
// eliminated): u=se-2*dot is quantized to an exactly-representable integer
// float q (2^-19 grid) and packed as q*16+tile; k1p/k2p track min/2nd-min
// via v_min/v_max only. k1-in-margin -> emit code; k2-in-margin -> the
// stream's 16 codes are all enumerated (no 3rd-code miss possible); cnt
// overflow -> exact full-1024 rescan. launch_bounds(256,1): occupancy is
// LDS-bound (2 blocks/CU) so the 128-VGPR cap that caused R5/R6/R8 spill
// collapse is removed.
__launch_bounds__(256, 1)
__global__ void vq_score(const float* __restrict__ x,
                         const float* __restrict__ cb,
                         const float* __restrict__ se_arr,
                         const unsigned short* __restrict__ cbbf,
                         float* __restrict__ out_q,
                         float* __restrict__ out_idx,
                         double* __restrict__ loss_acc)
{
    // wave-private double buffers: [wave][buf][k-step s][lane] = short8
    __shared__ short8 bufs[4][2][8][64];     // 65536 B
    __shared__ float minw[4][RPB];
    __shared__ float thr[RPB];
    __shared__ float sxl[RPB];
    __shared__ float sal[RPB];
    __shared__ unsigned int cnt[RPB];
    __shared__ unsigned int cand[RPB][CANDC];
    __shared__ unsigned long long win[RPB];
    __shared__ unsigned int wcode[RPB];
    __shared__ double lsum[4];

    const int tid  = threadIdx.x;
    const int w    = tid >> 6;
    const int lane = tid & 63;
    const int cc   = lane & 15;
    const int g    = lane >> 4;
    const int n0   = blockIdx.x * RPB;

    if (tid < RPB) { cnt[tid] = 0u; win[tid] = ~0ull; }

    // ---- A fragments: rows rt*16+cc, k = 32s + 8g + e (verified mapping) ----
    short8 afrag[2][8];
    #pragma unroll
    for (int rt = 0; rt < 2; ++rt) {
        const float4* rp = (const float4*)x + (size_t)(n0 + rt * 16 + cc) * 64;
        #pragma unroll
        for (int s = 0; s < 8; ++s) {
            float4 a = rp[s * 8 + g * 2];
            float4 b = rp[s * 8 + g * 2 + 1];
            short8 f;
            f[0] = (short)bf16rtne(a.x); f[1] = (short)bf16rtne(a.y);
            f[2] = (short)bf16rtne(a.z); f[3] = (short)bf16rtne(a.w);
            f[4] = (short)bf16rtne(b.x); f[5] = (short)bf16rtne(b.y);
            f[6] = (short)bf16rtne(b.z); f[7] = (short)bf16rtne(b.w);
            afrag[rt][s] = f;
        }
    }

    // ---- fused np-exact row sums (identical instruction sequence) ----
    {
        const int rowsub = lane >> 4;
        const int agent  = lane & 15;
        const int half   = agent >> 3;
        const int j      = agent & 7;
        #pragma unroll
        for (int q = 0; q < 2; ++q) {
            const int lrow = w * 8 + q * 4 + rowsub;
            const float* p = x + (size_t)(n0 + lrow) * DIM + half * 128 + j;
            float x0 = p[0];
            float r  = __fmul_rn(x0, x0);
            float ra = fabsf(x0);
            #pragma unroll
            for (int i = 1; i < 16; ++i) {
                float xi = p[8 * i];
                r  = __fadd_rn(r, __fmul_rn(xi, xi));
                ra += fabsf(xi);
            }
            r = __fadd_rn(r, __shfl_xor(r, 1, 64));  ra += __shfl_xor(ra, 1, 64);
            r = __fadd_rn(r, __shfl_xor(r, 2, 64));  ra += __shfl_xor(ra, 2, 64);
            r = __fadd_rn(r, __shfl_xor(r, 4, 64));  ra += __shfl_xor(ra, 4, 64);
            r = __fadd_rn(r, __shfl_xor(r, 8, 64));  ra += __shfl_xor(ra, 8, 64);
            if (agent == 0) { sxl[lrow] = r; sal[lrow] = ra; }
        }
    }

    const int T0 = w << 4;        // wave's first 16-code tile index
    const f32x4 fz = {0.f, 0.f, 0.f, 0.f};

    // se for the wave's 256-code slice: statically-indexed registers
    float se_reg[16];
    #pragma unroll
    for (int t = 0; t < 16; ++t) se_reg[t] = se_arr[(T0 + t) * 16 + cc];

    // packed top-2 trackers per (lane,row) stream: integer-valued floats
    // packed = q*16 + tile, q = trunc((clamp(u)+1)*2^19) < 2^20  (exact fp32)
    float k1p[2][4], k2p[2][4];
    #pragma unroll
    for (int rt = 0; rt < 2; ++rt)
        #pragma unroll
        for (int r = 0; r < 4; ++r) { k1p[rt][r] = INFINITY; k2p[rt][r] = INFINITY; }

#define ISSUE(T) do {                                                         \
    const char* gsrc_ = (const char*)cbbf + (size_t)(T0 + (T)) * 8192 + lane * 16; \
    _Pragma("unroll")                                                         \
    for (int i_ = 0; i_ < 8; ++i_)                                            \
        gload_lds16(gsrc_ + i_ * 1024, (void*)&bufs[w][(T) & 1][i_][0]);      \
} while (0)

#define WAITV_(N) asm volatile("s_waitcnt vmcnt(" #N ")" ::: "memory")
#define WAITV(N) WAITV_(N)
#define LGKM0 asm volatile("s_waitcnt lgkmcnt(0)" ::: "memory")

// fminf/fmaxf-only tracking — no cmp/cndmask chains (R6/R8 spill trigger)
#define COMPUTE(T) do {                                                       \
    short8 bv_[8];                                                            \
    _Pragma("unroll")                                                         \
    for (int s_ = 0; s_ < 8; ++s_) bv_[s_] = bufs[w][(T) & 1][s_][lane];      \
    f32x4 a0_ = fz, a1_ = fz;                                                 \
    _Pragma("unroll")                                                         \
    for (int s_ = 0; s_ < 8; ++s_) {                                          \
        a0_ = __builtin_amdgcn_mfma_f32_16x16x32_bf16(afrag[0][s_], bv_[s_], a0_, 0, 0, 0); \
        a1_ = __builtin_amdgcn_mfma_f32_16x16x32_bf16(afrag[1][s_], bv_[s_], a1_, 0, 0, 0); \
    }                                                                         \
    const float sec_ = se_reg[(T)];                                           \
    const float tf_  = (float)(T);                                            \
    _Pragma("unroll")                                                         \
    for (int r_ = 0; r_ < 4; ++r_) {                                          \
        float ua_ = fmaf(-2.f, a0_[r_], sec_);                                \
        float ub_ = fmaf(-2.f, a1_[r_], sec_);                                \
        float qa_ = truncf(fmaf(fminf(fmaxf(ua_, -0.999f), 0.999f), 524288.f, 524288.f)); \
        float qb_ = truncf(fmaf(fminf(fmaxf(ub_, -0.999f), 0.999f), 524288.f, 524288.f)); \
        float ka_ = fmaf(qa_, 16.f, tf_);                                     \
        float kb_ = fmaf(qb_, 16.f, tf_);                                     \
        float mxa_ = fmaxf(ka_, k1p[0][r_]);                                  \
        k1p[0][r_] = fminf(ka_, k1p[0][r_]);                                  \
        k2p[0][r_] = fminf(mxa_, k2p[0][r_]);                                 \
        float mxb_ = fmaxf(kb_, k1p[1][r_]);                                  \
        k1p[1][r_] = fminf(kb_, k1p[1][r_]);                                  \
        k2p[1][r_] = fminf(mxb_, k2p[1][r_]);                                 \
    }                                                                         \
} while (0)

// lgkmcnt(0): prev COMPUTE's ds_reads must land before overwriting its buf.
#define STEPW(T, W) do {                                                      \
    LGKM0;                                                                    \
    if ((T) < 15) ISSUE((T) + 1);                                             \
    WAITV(W);                                                                 \
    COMPUTE(T);                                                               \
} while (0)

    // ---- single MFMA pass: counted-vmcnt pipeline, no barriers ----
    WAITV(0);              // drain pre-loop VMEM so counts are exact
    ISSUE(0);
    STEPW(0, 8);  STEPW(1, 8);  STEPW(2, 8);  STEPW(3, 8);
    STEPW(4, 8);  STEPW(5, 8);  STEPW(6, 8);  STEPW(7, 8);
    STEPW(8, 8);  STEPW(9, 8);  STEPW(10, 8); STEPW(11, 8);
    STEPW(12, 8); STEPW(13, 8); STEPW(14, 8); STEPW(15, 0);

    // decode helpers: q = trunc(packed/16) (exact), u_dec = q*2^-19 - 1
#define QOF(kv)  truncf((kv) * 0.0625f)
#define UDEC(qv) fmaf((qv), 1.9073486328125e-6f, -1.0f)

    // ---- per-row u-min across the 16 cc-lanes, then across waves ----
    #pragma unroll
    for (int rt = 0; rt < 2; ++rt) {
        #pragma unroll
        for (int r = 0; r < 4; ++r) {
            float v = k1p[rt][r];
            v = fminf(v, __shfl_xor(v, 1, 64));
            v = fminf(v, __shfl_xor(v, 2, 64));
            v = fminf(v, __shfl_xor(v, 4, 64));
            v = fminf(v, __shfl_xor(v, 8, 64));
            if (cc == 0) minw[w][rt * 16 + g * 4 + r] = UDEC(QOF(v));
        }
    }
    __syncthreads();
    if (tid < RPB) {
        float umin = fminf(fminf(minw[0][tid], minw[1][tid]),
                           fminf(minw[2][tid], minw[3][tid]));
        // margin: 2*(bf16 dot err, <= sa*7.7e-6) + f32/quant rounding slack
        thr[tid] = umin + fmaf(sal[tid], 1.6e-5f, 1.0e-4f);
    }
    __syncthreads();

    // ---- candidate emission from stream trackers ----
    #pragma unroll
    for (int rt = 0; rt < 2; ++rt) {
        #pragma unroll
        for (int r = 0; r < 4; ++r) {
            const int row = rt * 16 + g * 4 + r;
            const float tu = thr[row];
            float k1 = k1p[rt][r];
            float q1 = QOF(k1);
            if (UDEC(q1) <= tu) {
                int t1 = (int)(k1 - q1 * 16.f);
                unsigned code = (unsigned)((T0 + t1) * 16 + cc);
                unsigned p = atomicAdd(&cnt[row], 1u);
                if (p < (unsigned)CANDC) cand[row][p] = code;
            }
            float k2 = k2p[rt][r];
            if (UDEC(QOF(k2)) <= tu) {
                // 2+ in-margin codes in this 16-code stream: enumerate it all
                for (int tt = 0; tt < 16; ++tt) {
                    unsigned code = (unsigned)((T0 + tt) * 16 + cc);
                    unsigned p = atomicAdd(&cnt[row], 1u);
                    if (p < (unsigned)CANDC) cand[row][p] = code;
                }
            }
        }
    }
    __syncthreads();

    // ---- PASS C: exact fp32 rescore of candidates (tie -> lower code) ----
    {
        const int r  = tid >> 3;
        const int sl = tid & 7;
        const unsigned int n = cnt[r];
        const bool ovf = (n > (unsigned)CANDC);
        const unsigned int total = ovf ? (unsigned)KCODES : n;
        const float sxr = sxl[r];
        const float4* xr  = (const float4*)x + (size_t)(n0 + r) * 64;
        const float4* cb4 = (const float4*)cb;
        for (unsigned int j = sl; j < total; j += 8) {
            unsigned int code = ovf ? j : cand[r][j];
            const float4* er = cb4 + (size_t)code * 64;
            float4 a4 = make_float4(0.f, 0.f, 0.f, 0.f);
            #pragma unroll 8
            for (int m2 = 0; m2 < 64; ++m2) {
                float4 xv = xr[m2];
                float4 ev = er[m2];
                FMA4(a4, xv, ev);
            }
            float dot  = (a4.x + a4.y) + (a4.z + a4.w);
            float tt   = __fadd_rn(sxr, se_arr[code]);
            float dist = __fsub_rn(tt, 2.0f * dot);
            unsigned long long pk =
                ((unsigned long long)__float_as_uint(dist) << 32) | (unsigned long long)code;
            atomicMin(&win[r], pk);
        }
    }
    __syncthreads();
    if (tid < RPB) {
        unsigned int code = (unsigned int)(win[tid] & 0xFFFFFFFFull);
        wcode[tid] = code;
        out_idx[n0 + tid] = (float)code;
    }
    __syncthreads();

    // ---- outputs (bit-exact straight-through) + fp64 loss partial ----
    double lacc = 0.0;
    {
        const float4* x4  = (const float4*)x;
        const float4* cb4 = (const float4*)cb;
        float4* q4 = (float4*)out_q;
        #pragma unroll
        for (int i = 0; i < 8; ++i) {
            int flat = tid + 256 * i;       // 0..2047 (32 rows x 64 float4)
            int row  = flat >> 6;
            int d4   = flat & 63;
            float4 xv = x4[(size_t)n0 * 64 + flat];
            float4 qv = cb4[(size_t)wcode[row] * 64 + d4];
            float dfx = __fsub_rn(qv.x, xv.x);
            float dfy = __fsub_rn(qv.y, xv.y);
            float dfz = __fsub_rn(qv.z, xv.z);
            float dfw = __fsub_rn(qv.w, xv.w);
            float4 o;
            o.x = __fadd_rn(xv.x, dfx);
            o.y = __fadd_rn(xv.y, dfy);
            o.z = __fadd_rn(xv.z, dfz);
            o.w = __fadd_rn(xv.w, dfw);
            lacc += (double)dfx * dfx + (double)dfy * dfy
                  + (double)dfz * dfz + (double)dfw * dfw;
            q4[(size_t)n0 * 64 + flat] = o;
        }
    }
    #pragma unroll
    for (int off = 32; off > 0; off >>= 1)
        lacc += __shfl_down(lacc, off, 64);
    if (lane == 0) lsum[w] = lacc;
    __syncthreads();
    if (tid == 0)
        atomicAdd(loss_acc, (lsum[0] + lsum[1]) + (lsum[2] + lsum[3]));
}

__global__ void finalize_loss(const double* __restrict__ acc,
                              float* __restrict__ out_loss) {
    if (threadIdx.x == 0 && blockIdx.x == 0)
        *out_loss = (float)(*acc / (double)(NROWS * DIM));
}

extern "C" void kernel_launch(void* const* d_in, const int* in_sizes, int n_in,
                              void* d_out, int out_size, void* d_ws, size_t ws_size,
                              hipStream_t stream) {
    const float* x  = (const float*)d_in[0];
    const float* cb = (const float*)d_in[1];
    float* out      = (float*)d_out;
    float* out_q    = out;                        // 8388608 elements
    float* out_idx  = out + (size_t)NROWS * DIM;  // 32768 elements (as float)
    float* out_loss = out_idx + NROWS;            // 1 element

    char* ws = (char*)d_ws;
    double* acc = (double*)ws;
    float* se   = (float*)(ws + WS_SE);
    unsigned short* cbbf = (unsigned short*)(ws + WS_CBBF);

    prep_kernel<<<64, 256, 0, stream>>>(cb, se, cbbf, acc);
    vq_score<<<NROWS / RPB, 256, 0, stream>>>(x, cb, se, cbbf,
                                              out_q, out_idx, acc);
    finalize_loss<<<1, 1, 0, stream>>>(acc, out_loss);
}